// Round 8
// baseline (90.945 us; speedup 1.0000x reference)
//
#include <hip/hip_runtime.h>
#include <cstdint>

// Ball query: B=8, N=4096, radius=0.2, nsample=32. Queries == sources.
// Output int32 (B,N,32): first 32 in-radius indices ascending, padded with
// the first match.
//
// Wave-per-query ballot: round k, lane l tests point k*64+l; 64-bit ballot
// lives in lane k's register. Early-exit per 512-point chunk.
//
// NUMERICS (R8): binding np ref deduced to be expansion-form f32 with
//   sq  = (x*x + y*y) + z*z        -- PLAIN (XLA elementwise+reduce, no fma)
//   dot = fma(qz,sz, fma(qy,sy, qx*sx))  -- Eigen/BLAS gebp pmadd, K asc
//   d2  = (sqq + sqs) - 2*dot      -- combine unambiguous (2*dot exact)
//   match = d2 < 0.04f
// Grid of evidence: (plain,plain)=288, (fma,fma)=288, f64=180, direct=180
// -> ref is expansion with a profile != both tested cells; (plain sq,
// fma dot) is what JAX-CPU (plain reduce + Eigen FMA matmul) produces.
// All rounding-sensitive ops in inline asm (immune to -ffast-math).

#define BQ_N   4096
#define BQ_B   8
#define BQ_NS  32
#define BQ_R2  0.04f

__device__ __forceinline__ float sq_plain(float x, float y, float z) {
    float r, t;
    asm("v_mul_f32 %0, %2, %2\n\t"     // x*x (rounded)
        "v_mul_f32 %1, %3, %3\n\t"     // y*y (rounded)
        "v_add_f32 %0, %0, %1\n\t"     // +
        "v_mul_f32 %1, %4, %4\n\t"     // z*z (rounded)
        "v_add_f32 %0, %0, %1"         // +
        : "=&v"(r), "=&v"(t)
        : "v"(x), "v"(y), "v"(z));
    return r;
}

__device__ __forceinline__ float d2_mixed(float qx, float qy, float qz, float sqq,
                                          float sx, float sy, float sz, float sqs) {
    float r, t;
    asm("v_mul_f32 %0, %2, %5\n\t"     // qx*sx
        "v_fma_f32 %0, %3, %6, %0\n\t" // + qy*sy   (fused)
        "v_fma_f32 %0, %4, %7, %0\n\t" // + qz*sz   (fused) = dot
        "v_add_f32 %0, %0, %0\n\t"     // 2*dot (exact)
        "v_add_f32 %1, %8, %9\n\t"     // t = sqq + sqs
        "v_sub_f32 %0, %1, %0"         // d2 = t - 2*dot
        : "=&v"(r), "=&v"(t)
        : "v"(qx), "v"(qy), "v"(qz), "v"(sx), "v"(sy), "v"(sz),
          "v"(sqq), "v"(sqs));
    return r;
}

__global__ __launch_bounds__(256, 2)
void ball_query_kernel(const float* __restrict__ xyz, int* __restrict__ out)
{
    __shared__ float4 pts[BQ_N];   // 64 KiB: (x, y, z, |p|^2) -> 2 blocks/CU

    const int b     = blockIdx.x >> 6;         // 64 blocks per batch
    const int qbase = (blockIdx.x & 63) << 6;  // 64 queries per block
    const float* __restrict__ src = xyz + (size_t)b * BQ_N * 3;

    for (int j = threadIdx.x; j < BQ_N; j += 256) {
        const float x = src[3 * j + 0];
        const float y = src[3 * j + 1];
        const float z = src[3 * j + 2];
        pts[j] = make_float4(x, y, z, sq_plain(x, y, z));
    }
    __syncthreads();

    const int lane = threadIdx.x & 63;
    const int wid  = threadIdx.x >> 6;  // 0..3, one wave per SIMD
    int* __restrict__ outb = out + (size_t)(b * BQ_N) * BQ_NS;

    for (int qi = 0; qi < 16; ++qi) {
        const int m = qbase + (wid << 4) + qi;
        const float4 q = pts[m];       // broadcast read (conflict-free)
        const float sqq = q.w;

        uint64_t word = 0;             // match mask for span [lane*64, +64)
        int found = 0;                 // wave-uniform running match count
        for (int c = 0; c < 8; ++c) {
            #pragma unroll
            for (int u = 0; u < 8; ++u) {
                const int k = c * 8 + u;
                const float4 s = pts[(k << 6) + lane];
                const float d2 = d2_mixed(q.x, q.y, q.z, sqq,
                                          s.x, s.y, s.z, s.w);
                const uint64_t bal = __ballot(d2 < BQ_R2);
                if (lane == k) word = bal;
                found += __popcll(bal);       // uniform -> scalar s_bcnt
            }
            if (found >= BQ_NS) break;        // uniform branch: enough matches
        }

        // Exclusive prefix of per-lane popcounts -> each lane's output slots.
        const int cnt = __popcll(word);
        int incl = cnt;
        #pragma unroll
        for (int off = 1; off < 64; off <<= 1) {
            const int t = __shfl_up(incl, off);
            if (lane >= off) incl += t;
        }
        const int pre   = incl - cnt;
        const int total = __shfl(incl, 63);

        // Global first match (|d2_self| <= ~2e-7 << 0.04 -> never empty).
        int first;
        const uint64_t nz = __ballot(word != 0ull);
        if (nz == 0ull) {
            first = BQ_N;   // defensive; unreachable
        } else {
            const int fl = __builtin_ctzll(nz);
            const uint64_t fw = __shfl(word, fl);
            first = (fl << 6) + __builtin_ctzll(fw);
        }

        int* __restrict__ orow = outb + m * BQ_NS;
        uint64_t w = word;
        int pos = pre;
        while (w != 0ull && pos < BQ_NS) {
            const int bit = __builtin_ctzll(w);
            orow[pos] = (lane << 6) + bit;
            w &= (w - 1);
            ++pos;
        }
        if (lane == 0) {
            for (int p = total; p < BQ_NS; ++p) orow[p] = first;
        }
    }
}

extern "C" void kernel_launch(void* const* d_in, const int* in_sizes, int n_in,
                              void* d_out, int out_size, void* d_ws, size_t ws_size,
                              hipStream_t stream)
{
    const float* xyz = (const float*)d_in[0];   // (8, 4096, 3) f32; d_in[1] unused
    int* out = (int*)d_out;                     // (8, 4096, 32) int32
    hipLaunchKernelGGL(ball_query_kernel, dim3(BQ_B * 64), dim3(256), 0, stream,
                       xyz, out);
}

// Round 10
// 89.389 us; speedup vs baseline: 1.0174x; 1.0174x over previous
//
#include <hip/hip_runtime.h>
#include <cstdint>

// Ball query: B=8, N=4096, radius=0.2, nsample=32. Queries == sources.
// Output int32 (B,N,32): first 32 in-radius indices ascending, padded with
// the first match.
//
// NUMERICS (LOCKED, R8-verified absmax=0): expansion form f32,
//   sq  = (x*x + y*y) + z*z              -- plain, no FMA
//   dot = fma(qz,sz, fma(qy,sy, qx*sx))  -- FMA, K ascending
//   d2  = (sqq + sqs) - (dot + dot)
//   match = d2 < 0.04f
// All in inline asm -- immune to -ffast-math/contract. DO NOT CHANGE.
//
// R10 perf (= R9 design, writelane builtin removed — not available):
// R8 was LDS-pipe bound (1 ds_read_b128 ~12cyc/CU per ~10 VALU; VALUBusy
// 46% == model). 2 queries share each ds_read (LDS per query-round
// halves), 256-pt early-exit chunks, single-query fallback loop when one
// of the pair finishes.

#define BQ_N   4096
#define BQ_B   8
#define BQ_NS  32
#define BQ_R2  0.04f

__device__ __forceinline__ float sq_plain(float x, float y, float z) {
    float r, t;
    asm("v_mul_f32 %0, %2, %2\n\t"
        "v_mul_f32 %1, %3, %3\n\t"
        "v_add_f32 %0, %0, %1\n\t"
        "v_mul_f32 %1, %4, %4\n\t"
        "v_add_f32 %0, %0, %1"
        : "=&v"(r), "=&v"(t)
        : "v"(x), "v"(y), "v"(z));
    return r;
}

__device__ __forceinline__ float d2_mixed(float qx, float qy, float qz, float sqq,
                                          float sx, float sy, float sz, float sqs) {
    float r, t;
    asm("v_mul_f32 %0, %2, %5\n\t"     // qx*sx
        "v_fma_f32 %0, %3, %6, %0\n\t" // + qy*sy (fused)
        "v_fma_f32 %0, %4, %7, %0\n\t" // + qz*sz (fused) = dot
        "v_add_f32 %0, %0, %0\n\t"     // 2*dot (exact)
        "v_add_f32 %1, %8, %9\n\t"     // sqq + sqs
        "v_sub_f32 %0, %1, %0"         // d2
        : "=&v"(r), "=&v"(t)
        : "v"(qx), "v"(qy), "v"(qz), "v"(sx), "v"(sy), "v"(sz),
          "v"(sqq), "v"(sqs));
    return r;
}

__device__ __forceinline__ void scan_chunk1(const float4* pts, int lane,
                                            float4 q, int c,
                                            uint64_t& word, int& found) {
    #pragma unroll
    for (int u = 0; u < 4; ++u) {
        const int k = (c << 2) + u;
        const float4 s = pts[(k << 6) + lane];
        const float d2 = d2_mixed(q.x, q.y, q.z, q.w, s.x, s.y, s.z, s.w);
        const uint64_t bal = __ballot(d2 < BQ_R2);
        if (lane == k) word = bal;
        found += (int)__popcll(bal);
    }
}

__device__ __forceinline__ void emit_query(int* orow, int lane, uint64_t word) {
    const int cnt = __popcll(word);
    int incl = cnt;
    #pragma unroll
    for (int off = 1; off < 64; off <<= 1) {
        const int t = __shfl_up(incl, off);
        if (lane >= off) incl += t;
    }
    const int pre   = incl - cnt;
    const int total = __shfl(incl, 63);

    int first;
    const uint64_t nz = __ballot(word != 0ull);
    if (nz == 0ull) {
        first = BQ_N;   // defensive; self-match makes this unreachable
    } else {
        const int fl = __builtin_ctzll(nz);
        const uint64_t fw = __shfl(word, fl);
        first = (fl << 6) + __builtin_ctzll(fw);
    }

    uint64_t w = word;
    int pos = pre;
    while (w != 0ull && pos < BQ_NS) {
        const int bit = __builtin_ctzll(w);
        orow[pos] = (lane << 6) + bit;
        w &= (w - 1);
        ++pos;
    }
    if (lane == 0) {
        for (int p = total; p < BQ_NS; ++p) orow[p] = first;
    }
}

__global__ __launch_bounds__(256, 2)
void ball_query_kernel(const float* __restrict__ xyz, int* __restrict__ out)
{
    __shared__ float4 pts[BQ_N];   // 64 KiB: (x, y, z, |p|^2) -> 2 blocks/CU

    const int b     = blockIdx.x >> 6;         // 64 blocks per batch
    const int qbase = (blockIdx.x & 63) << 6;  // 64 queries per block
    const float* __restrict__ src = xyz + (size_t)b * BQ_N * 3;

    for (int j = threadIdx.x; j < BQ_N; j += 256) {
        const float x = src[3 * j + 0];
        const float y = src[3 * j + 1];
        const float z = src[3 * j + 2];
        pts[j] = make_float4(x, y, z, sq_plain(x, y, z));
    }
    __syncthreads();

    const int lane = threadIdx.x & 63;
    const int wid  = threadIdx.x >> 6;  // 0..3, one wave per SIMD
    int* __restrict__ outb = out + (size_t)(b * BQ_N) * BQ_NS;

    for (int p = 0; p < 8; ++p) {       // 8 query-pairs per wave
        const int m0 = qbase + (wid << 4) + p;
        const int m1 = m0 + 8;
        const float4 q0 = pts[m0];      // broadcast reads
        const float4 q1 = pts[m1];

        uint64_t word0 = 0, word1 = 0;
        int found0 = 0, found1 = 0;

        // Dual phase: both queries share each ds_read_b128.
        int c = 0;
        while (c < 16) {                // 16 chunks x 4 rounds x 64 pts
            #pragma unroll
            for (int u = 0; u < 4; ++u) {
                const int k = (c << 2) + u;
                const float4 s = pts[(k << 6) + lane];
                const float d20 = d2_mixed(q0.x, q0.y, q0.z, q0.w,
                                           s.x, s.y, s.z, s.w);
                const float d21 = d2_mixed(q1.x, q1.y, q1.z, q1.w,
                                           s.x, s.y, s.z, s.w);
                const uint64_t bal0 = __ballot(d20 < BQ_R2);
                const uint64_t bal1 = __ballot(d21 < BQ_R2);
                if (lane == k) { word0 = bal0; word1 = bal1; }
                found0 += (int)__popcll(bal0);
                found1 += (int)__popcll(bal1);
            }
            ++c;
            if (found0 >= BQ_NS || found1 >= BQ_NS) break;   // uniform
        }
        // Single-query fallback for whichever is unfinished (uniform).
        for (int c0 = c; c0 < 16 && found0 < BQ_NS; ++c0)
            scan_chunk1(pts, lane, q0, c0, word0, found0);
        for (int c1 = c; c1 < 16 && found1 < BQ_NS; ++c1)
            scan_chunk1(pts, lane, q1, c1, word1, found1);

        emit_query(outb + (size_t)m0 * BQ_NS, lane, word0);
        emit_query(outb + (size_t)m1 * BQ_NS, lane, word1);
    }
}

extern "C" void kernel_launch(void* const* d_in, const int* in_sizes, int n_in,
                              void* d_out, int out_size, void* d_ws, size_t ws_size,
                              hipStream_t stream)
{
    const float* xyz = (const float*)d_in[0];   // (8, 4096, 3) f32; d_in[1] unused
    int* out = (int*)d_out;                     // (8, 4096, 32) int32
    hipLaunchKernelGGL(ball_query_kernel, dim3(BQ_B * 64), dim3(256), 0, stream,
                       xyz, out);
}

// Round 11
// 84.057 us; speedup vs baseline: 1.0819x; 1.0634x over previous
//
#include <hip/hip_runtime.h>
#include <cstdint>

// Ball query: B=8, N=4096, radius=0.2, nsample=32. Queries == sources.
// Output int32 (B,N,32): first 32 in-radius indices ascending, padded with
// the first match.
//
// NUMERICS (LOCKED, R8-verified absmax=0): expansion form f32,
//   sq  = (x*x + y*y) + z*z              -- plain, no FMA
//   dot = fma(qz,sz, fma(qy,sy, qx*sx))  -- FMA, K ascending
//   d2  = (sqq + sqs) - (dot + dot)
//   match = d2 < 0.04f
// All in inline asm -- immune to -ffast-math/contract. DO NOT CHANGE.
//
// R11 perf: R10 was LATENCY-bound (VALU 16.6us + LDS 9us vs 40us wall;
// occupancy 16% = 2 blocks/CU by 64KiB LDS). Half-tile restage: 32KiB LDS
// (2048 pts), two phases with block-wide restage barrier; 1024 blocks x
// 32 queries -> 4 blocks/CU, 16 waves/CU, all blocks resident. Pairs
// finished in phase A skip phase B (register state, uniform branches).

#define BQ_N    4096
#define BQ_HALF 2048
#define BQ_B    8
#define BQ_NS   32
#define BQ_R2   0.04f

__device__ __forceinline__ float sq_plain(float x, float y, float z) {
    float r, t;
    asm("v_mul_f32 %0, %2, %2\n\t"
        "v_mul_f32 %1, %3, %3\n\t"
        "v_add_f32 %0, %0, %1\n\t"
        "v_mul_f32 %1, %4, %4\n\t"
        "v_add_f32 %0, %0, %1"
        : "=&v"(r), "=&v"(t)
        : "v"(x), "v"(y), "v"(z));
    return r;
}

__device__ __forceinline__ float d2_mixed(float qx, float qy, float qz, float sqq,
                                          float sx, float sy, float sz, float sqs) {
    float r, t;
    asm("v_mul_f32 %0, %2, %5\n\t"     // qx*sx
        "v_fma_f32 %0, %3, %6, %0\n\t" // + qy*sy (fused)
        "v_fma_f32 %0, %4, %7, %0\n\t" // + qz*sz (fused) = dot
        "v_add_f32 %0, %0, %0\n\t"     // 2*dot (exact)
        "v_add_f32 %1, %8, %9\n\t"     // sqq + sqs
        "v_sub_f32 %0, %1, %0"         // d2
        : "=&v"(r), "=&v"(t)
        : "v"(qx), "v"(qy), "v"(qz), "v"(sx), "v"(sy), "v"(sz),
          "v"(sqq), "v"(sqs));
    return r;
}

// One 64-pt round inside chunk c (global chunk id 0..15; LDS holds the
// current 2048-pt half, so the LDS index uses k & 31).
__device__ __forceinline__ void scan1(const float4* pts, int lane,
                                      const float4& q, int c,
                                      uint64_t& word, int& found) {
    #pragma unroll
    for (int u = 0; u < 4; ++u) {
        const int k = (c << 2) + u;
        const float4 s = pts[((k & 31) << 6) + lane];
        const float d2 = d2_mixed(q.x, q.y, q.z, q.w, s.x, s.y, s.z, s.w);
        const uint64_t bal = __ballot(d2 < BQ_R2);
        if (lane == k) word = bal;
        found += (int)__popcll(bal);
    }
}

// Dual-query cascade over chunk range [c0, c1): both share each ds_read;
// after the OR-break, singles finish independently. Entry: both found < 32.
__device__ __forceinline__ void scan2(const float4* pts, int lane,
                                      const float4& q0, const float4& q1,
                                      int c0, int c1,
                                      uint64_t& w0, uint64_t& w1,
                                      int& f0, int& f1) {
    int c = c0;
    while (c < c1) {
        #pragma unroll
        for (int u = 0; u < 4; ++u) {
            const int k = (c << 2) + u;
            const float4 s = pts[((k & 31) << 6) + lane];
            const float d20 = d2_mixed(q0.x, q0.y, q0.z, q0.w,
                                       s.x, s.y, s.z, s.w);
            const float d21 = d2_mixed(q1.x, q1.y, q1.z, q1.w,
                                       s.x, s.y, s.z, s.w);
            const uint64_t b0 = __ballot(d20 < BQ_R2);
            const uint64_t b1 = __ballot(d21 < BQ_R2);
            if (lane == k) { w0 = b0; w1 = b1; }
            f0 += (int)__popcll(b0);
            f1 += (int)__popcll(b1);
        }
        ++c;
        if (f0 >= BQ_NS || f1 >= BQ_NS) break;   // uniform
    }
    for (int ca = c; ca < c1 && f0 < BQ_NS; ++ca) scan1(pts, lane, q0, ca, w0, f0);
    for (int cb = c; cb < c1 && f1 < BQ_NS; ++cb) scan1(pts, lane, q1, cb, w1, f1);
}

__device__ __forceinline__ void emit_query(int* orow, int lane, uint64_t word) {
    const int cnt = __popcll(word);
    int incl = cnt;
    #pragma unroll
    for (int off = 1; off < 64; off <<= 1) {
        const int t = __shfl_up(incl, off);
        if (lane >= off) incl += t;
    }
    const int pre   = incl - cnt;
    const int total = __shfl(incl, 63);

    int first;
    const uint64_t nz = __ballot(word != 0ull);
    if (nz == 0ull) {
        first = BQ_N;   // defensive; self-match (|d2|<=2e-7) makes this unreachable
    } else {
        const int fl = __builtin_ctzll(nz);
        const uint64_t fw = __shfl(word, fl);
        first = (fl << 6) + __builtin_ctzll(fw);
    }

    uint64_t w = word;
    int pos = pre;
    while (w != 0ull && pos < BQ_NS) {
        const int bit = __builtin_ctzll(w);
        orow[pos] = (lane << 6) + bit;
        w &= (w - 1);
        ++pos;
    }
    // vectorized padding: lanes [total, 32) store `first`
    if (lane >= total && lane < BQ_NS) orow[lane] = first;
}

__global__ __launch_bounds__(256, 4)
void ball_query_kernel(const float* __restrict__ xyz, int* __restrict__ out)
{
    __shared__ float4 pts[BQ_HALF];   // 32 KiB -> 4 blocks/CU (grid-limited)

    const int b     = blockIdx.x >> 7;          // 128 blocks per batch
    const int qbase = (blockIdx.x & 127) << 5;  // 32 queries per block
    const float* __restrict__ src = xyz + (size_t)b * BQ_N * 3;
    const int lane = threadIdx.x & 63;
    const int wid  = threadIdx.x >> 6;
    int* __restrict__ outb = out + (size_t)(b * BQ_N) * BQ_NS;

    // Wave's 8 query points from global (wave-uniform addresses -> L2).
    float4 Q[8];
    #pragma unroll
    for (int j = 0; j < 8; ++j) {
        const int m = qbase + (wid << 3) + j;
        const float x = src[3 * m + 0];
        const float y = src[3 * m + 1];
        const float z = src[3 * m + 2];
        Q[j] = make_float4(x, y, z, sq_plain(x, y, z));
    }

    // Stage phase-A half (points 0..2047).
    for (int j = threadIdx.x; j < BQ_HALF; j += 256) {
        const float x = src[3 * j + 0];
        const float y = src[3 * j + 1];
        const float z = src[3 * j + 2];
        pts[j] = make_float4(x, y, z, sq_plain(x, y, z));
    }
    __syncthreads();

    uint64_t W[8] = {0, 0, 0, 0, 0, 0, 0, 0};
    int      F[8] = {0, 0, 0, 0, 0, 0, 0, 0};

    // Phase A: chunks 0..7 (points 0..2047), 4 pairs back-to-back.
    #pragma unroll
    for (int p = 0; p < 4; ++p)
        scan2(pts, lane, Q[p], Q[p + 4], 0, 8, W[p], W[p + 4], F[p], F[p + 4]);

    // Restage phase-B half (points 2048..4095).
    __syncthreads();   // all waves done reading phase-A pts
    for (int j = threadIdx.x; j < BQ_HALF; j += 256) {
        const int g = BQ_HALF + j;
        const float x = src[3 * g + 0];
        const float y = src[3 * g + 1];
        const float z = src[3 * g + 2];
        pts[j] = make_float4(x, y, z, sq_plain(x, y, z));
    }
    __syncthreads();

    // Phase B: chunks 8..15, only for unfinished queries (uniform branches).
    #pragma unroll
    for (int p = 0; p < 4; ++p) {
        if (F[p] < BQ_NS && F[p + 4] < BQ_NS) {
            scan2(pts, lane, Q[p], Q[p + 4], 8, 16,
                  W[p], W[p + 4], F[p], F[p + 4]);
        } else if (F[p] < BQ_NS) {
            for (int ca = 8; ca < 16 && F[p] < BQ_NS; ++ca)
                scan1(pts, lane, Q[p], ca, W[p], F[p]);
        } else if (F[p + 4] < BQ_NS) {
            for (int cb = 8; cb < 16 && F[p + 4] < BQ_NS; ++cb)
                scan1(pts, lane, Q[p + 4], cb, W[p + 4], F[p + 4]);
        }
    }

    #pragma unroll
    for (int j = 0; j < 8; ++j) {
        const int m = qbase + (wid << 3) + j;
        emit_query(outb + (size_t)m * BQ_NS, lane, W[j]);
    }
}

extern "C" void kernel_launch(void* const* d_in, const int* in_sizes, int n_in,
                              void* d_out, int out_size, void* d_ws, size_t ws_size,
                              hipStream_t stream)
{
    const float* xyz = (const float*)d_in[0];   // (8, 4096, 3) f32; d_in[1] unused
    int* out = (int*)d_out;                     // (8, 4096, 32) int32
    hipLaunchKernelGGL(ball_query_kernel, dim3(1024), dim3(256), 0, stream,
                       xyz, out);
}